// Round 1
// baseline (427.494 us; speedup 1.0000x reference)
//
#include <hip/hip_runtime.h>

// GAT (2-layer, PyG GATConv semantics) on MI355X.
// N=20000 nodes, E=100000 edges (+N self-loops), D=64, H=16 heads, C=64 ch/head.
constexpr int TD  = 64;     // input feature dim
constexpr int TH  = 16;     // heads
constexpr int TC  = 64;     // channels per head
constexpr int THC = TH * TC; // 1024

// ---------------- CSR build ----------------

__global__ void k_zero_int(int* p, int n) {
  int i = blockIdx.x * blockDim.x + threadIdx.x;
  if (i < n) p[i] = 0;
}

__global__ void k_count_deg(const int* __restrict__ dst, int E, int N, int* __restrict__ deg) {
  int e = blockIdx.x * blockDim.x + threadIdx.x;
  if (e >= E + N) return;
  int d = (e < E) ? dst[e] : (e - E);   // self-loop edges e in [E, E+N)
  atomicAdd(&deg[d], 1);
}

// single-block exclusive scan over N=20000 degrees -> row_start[N+1], cursor copy
__global__ void k_scan(const int* __restrict__ deg, int N, int* __restrict__ row_start,
                       int* __restrict__ cursor) {
  __shared__ int part[256];
  int t = threadIdx.x;
  int chunk = (N + 255) / 256;
  int lo = t * chunk, hi = min(lo + chunk, N);
  int s = 0;
  for (int i = lo; i < hi; ++i) s += deg[i];
  part[t] = s;
  __syncthreads();
  if (t == 0) {
    int run = 0;
    for (int i = 0; i < 256; ++i) { int v = part[i]; part[i] = run; run += v; }
    row_start[N] = run;
  }
  __syncthreads();
  int run = part[t];
  for (int i = lo; i < hi; ++i) {
    row_start[i] = run; cursor[i] = run; run += deg[i];
  }
}

__global__ void k_scatter(const int* __restrict__ dst, int E, int N,
                          int* __restrict__ cursor, int* __restrict__ eid) {
  int e = blockIdx.x * blockDim.x + threadIdx.x;
  if (e >= E + N) return;
  int d = (e < E) ? dst[e] : (e - E);
  int pos = atomicAdd(&cursor[d], 1);
  eid[pos] = e;
}

// self-loop edge_attr = mean of incoming (original) edge_attr per dst (0 if none)
__global__ void k_loop_ea(const float* __restrict__ ea, const int* __restrict__ row_start,
                          const int* __restrict__ eid, int E, float* __restrict__ loop_ea) {
  int n = blockIdx.x;
  int t = threadIdx.x;       // 64 threads, one per feature d
  int beg = row_start[n], end = row_start[n + 1];
  float acc = 0.f; int cnt = 0;
  for (int i = beg; i < end; ++i) {
    int e = eid[i];
    if (e < E) { acc += ea[(size_t)e * TD + t]; cnt++; }
  }
  loop_ea[(size_t)n * TD + t] = acc / (float)max(cnt, 1);
}

// ---------------- per-layer kernels ----------------

// xp = x[N,64] @ W[64,1024], fp32 vector GEMM, 64x64 tiles
__global__ __launch_bounds__(256) void k_matmul(const float* __restrict__ x,
                                                const float* __restrict__ W,
                                                int N, float* __restrict__ xp) {
  __shared__ float xs[64][65];   // +1 pad: avoid bank conflicts on column reads
  __shared__ float ws[64][64];
  int r0 = blockIdx.x * 64;
  int c0 = blockIdx.y * 64;
  int tid = threadIdx.x;
  for (int idx = tid * 4; idx < 64 * 64; idx += 1024) {
    int r = idx >> 6, c = idx & 63;
    float4 v = make_float4(0.f, 0.f, 0.f, 0.f);
    if (r0 + r < N) v = *(const float4*)&x[(size_t)(r0 + r) * TD + c];
    xs[r][c] = v.x; xs[r][c + 1] = v.y; xs[r][c + 2] = v.z; xs[r][c + 3] = v.w;
    *(float4*)&ws[r][c] = *(const float4*)&W[(size_t)r * THC + c0 + c];  // r == k
  }
  __syncthreads();
  int ty = tid >> 4, tx = tid & 15;
  float acc[4][4] = {};
  for (int k = 0; k < 64; ++k) {
    float a0 = xs[ty * 4 + 0][k], a1 = xs[ty * 4 + 1][k];
    float a2 = xs[ty * 4 + 2][k], a3 = xs[ty * 4 + 3][k];
    float4 b = *(const float4*)&ws[k][tx * 4];
    acc[0][0] += a0 * b.x; acc[0][1] += a0 * b.y; acc[0][2] += a0 * b.z; acc[0][3] += a0 * b.w;
    acc[1][0] += a1 * b.x; acc[1][1] += a1 * b.y; acc[1][2] += a1 * b.z; acc[1][3] += a1 * b.w;
    acc[2][0] += a2 * b.x; acc[2][1] += a2 * b.y; acc[2][2] += a2 * b.z; acc[2][3] += a2 * b.w;
    acc[3][0] += a3 * b.x; acc[3][1] += a3 * b.y; acc[3][2] += a3 * b.z; acc[3][3] += a3 * b.w;
  }
  for (int i = 0; i < 4; ++i) {
    int r = r0 + ty * 4 + i;
    if (r < N)
      *(float4*)&xp[(size_t)r * THC + c0 + tx * 4] =
          make_float4(acc[i][0], acc[i][1], acc[i][2], acc[i][3]);
  }
}

// al_s[n,h] = <xp[n,h,:], a_src[h,:]>, al_d likewise
__global__ __launch_bounds__(256) void k_al_sd(const float* __restrict__ xp,
                                               const float* __restrict__ a_src,
                                               const float* __restrict__ a_dst,
                                               float* __restrict__ al_s, float* __restrict__ al_d) {
  int n = blockIdx.x;
  int tid = threadIdx.x;           // 256 = 16 heads x 16 lanes
  int h = tid >> 4, c4 = (tid & 15) * 4;
  float4 v  = *(const float4*)&xp[(size_t)n * THC + h * TC + c4];
  float4 as = *(const float4*)&a_src[h * TC + c4];
  float4 ad = *(const float4*)&a_dst[h * TC + c4];
  float ps = v.x * as.x + v.y * as.y + v.z * as.z + v.w * as.w;
  float pd = v.x * ad.x + v.y * ad.y + v.z * ad.z + v.w * ad.w;
  for (int m = 8; m >= 1; m >>= 1) {
    ps += __shfl_xor(ps, m, 16);
    pd += __shfl_xor(pd, m, 16);
  }
  if ((tid & 15) == 0) { al_s[n * TH + h] = ps; al_d[n * TH + h] = pd; }
}

// w_e[d,h] = sum_c We[d, h*64+c] * a_e[h,c]
__global__ void k_we(const float* __restrict__ We, const float* __restrict__ a_e,
                     float* __restrict__ w_e) {
  int t = blockIdx.x * blockDim.x + threadIdx.x;
  if (t >= TD * TH) return;
  int d = t >> 4, h = t & 15;
  float s = 0.f;
  for (int c = 0; c < TC; ++c) s += We[(size_t)d * THC + h * TC + c] * a_e[h * TC + c];
  w_e[d * TH + h] = s;
}

// al_e[e,h] = <ea_row(e), w_e[:,h]>, 16 edges per block
__global__ __launch_bounds__(256) void k_al_e(const float* __restrict__ ea,
                                              const float* __restrict__ loop_ea,
                                              const float* __restrict__ w_e,
                                              int E, int EN, float* __restrict__ al_e) {
  __shared__ float sea[16][65];
  __shared__ float swe[TD * TH];
  int tid = threadIdx.x;
  int e0 = blockIdx.x * 16;
  for (int i = tid; i < TD * TH; i += 256) swe[i] = w_e[i];
  for (int i = tid; i < 16 * 64; i += 256) {
    int le = i >> 6, d = i & 63;
    int e = e0 + le;
    float v = 0.f;
    if (e < EN) {
      const float* row = (e < E) ? &ea[(size_t)e * TD] : &loop_ea[(size_t)(e - E) * TD];
      v = row[d];
    }
    sea[le][d] = v;
  }
  __syncthreads();
  int le = tid >> 4, h = tid & 15;
  int e = e0 + le;
  if (e >= EN) return;
  float s = 0.f;
  for (int d = 0; d < TD; ++d) s += sea[le][d] * swe[d * TH + h];
  al_e[(size_t)e * TH + h] = s;
}

// per-dst-node: online segment softmax over in-edges, then weighted gather of
// xp[src] rows, head-mean, +bias, relu
__global__ __launch_bounds__(256) void k_aggregate(
    const float* __restrict__ xp, const float* __restrict__ al_s,
    const float* __restrict__ al_d, const float* __restrict__ al_e,
    const int* __restrict__ row_start, const int* __restrict__ eid,
    const int* __restrict__ src, int E,
    const float* __restrict__ bias, float* __restrict__ out) {
  __shared__ float sm[TH], sden[TH];
  __shared__ float red[THC];
  int n = blockIdx.x;
  int tid = threadIdx.x;
  int beg = row_start[n], end = row_start[n + 1];

  if (tid < TH) {   // phase A: online max + denominator per head
    int h = tid;
    float ald = al_d[n * TH + h];
    float m = -1e30f, den = 0.f;
    for (int i = beg; i < end; ++i) {
      int e = eid[i];
      int s = (e < E) ? src[e] : (e - E);
      float a = al_s[s * TH + h] + ald + al_e[(size_t)e * TH + h];
      a = (a > 0.f) ? a : 0.2f * a;          // leaky_relu 0.2
      float nm = fmaxf(m, a);
      den = den * expf(m - nm) + expf(a - nm);
      m = nm;
    }
    sm[h] = m;
    sden[h] = den + 1e-16f;
  }
  __syncthreads();

  int h = tid >> 4, c4 = (tid & 15) * 4;     // phase B: weighted gather
  float ald = al_d[n * TH + h];
  float m = sm[h];
  float deninv = 1.0f / sden[h];
  float4 acc = make_float4(0.f, 0.f, 0.f, 0.f);
  for (int i = beg; i < end; ++i) {
    int e = eid[i];
    int s = (e < E) ? src[e] : (e - E);
    float a = al_s[s * TH + h] + ald + al_e[(size_t)e * TH + h];
    a = (a > 0.f) ? a : 0.2f * a;
    float wgt = expf(a - m) * deninv;
    float4 v = *(const float4*)&xp[(size_t)s * THC + h * TC + c4];
    acc.x += wgt * v.x; acc.y += wgt * v.y; acc.z += wgt * v.z; acc.w += wgt * v.w;
  }
  *(float4*)&red[tid * 4] = acc;
  __syncthreads();
  if (tid < TC) {   // head mean + bias + relu
    float s = 0.f;
    for (int hh = 0; hh < TH; ++hh) s += red[hh * TC + tid];
    s = s * (1.0f / TH) + bias[tid];
    out[(size_t)n * TC + tid] = fmaxf(s, 0.f);
  }
}

// ---------------- launch ----------------

extern "C" void kernel_launch(void* const* d_in, const int* in_sizes, int n_in,
                              void* d_out, int out_size, void* d_ws, size_t ws_size,
                              hipStream_t stream) {
  const float* x   = (const float*)d_in[0];
  const int*   ei  = (const int*)d_in[1];
  const float* ea  = (const float*)d_in[2];
  const float* W1  = (const float*)d_in[3];
  const float* as1 = (const float*)d_in[4];
  const float* ad1 = (const float*)d_in[5];
  const float* We1 = (const float*)d_in[6];
  const float* ae1 = (const float*)d_in[7];
  const float* b1  = (const float*)d_in[8];
  const float* W2  = (const float*)d_in[9];
  const float* as2 = (const float*)d_in[10];
  const float* ad2 = (const float*)d_in[11];
  const float* We2 = (const float*)d_in[12];
  const float* ae2 = (const float*)d_in[13];
  const float* b2  = (const float*)d_in[14];

  const int N  = in_sizes[0] / TD;   // 20000
  const int E  = in_sizes[1] / 2;    // 100000
  const int EN = E + N;              // 120000 (with self-loops)
  const int* srcA = ei;
  const int* dstA = ei + E;

  char* w = (char*)d_ws;
  auto alloc = [&](size_t bytes) {
    char* p = w;
    w += (bytes + 255) & ~(size_t)255;
    return p;
  };
  int*   deg       = (int*)alloc((size_t)N * 4);
  int*   row_start = (int*)alloc((size_t)(N + 1) * 4);
  int*   cursor    = (int*)alloc((size_t)N * 4);
  int*   eid       = (int*)alloc((size_t)EN * 4);
  float* loop_ea   = (float*)alloc((size_t)N * TD * 4);
  float* xp        = (float*)alloc((size_t)N * THC * 4);
  float* al_s      = (float*)alloc((size_t)N * TH * 4);
  float* al_d      = (float*)alloc((size_t)N * TH * 4);
  float* al_e      = (float*)alloc((size_t)EN * TH * 4);
  float* w_e       = (float*)alloc((size_t)TD * TH * 4);
  float* hbuf      = (float*)alloc((size_t)N * TC * 4);

  // CSR by destination (shared by both layers)
  k_zero_int<<<(N + 255) / 256, 256, 0, stream>>>(deg, N);
  k_count_deg<<<(EN + 255) / 256, 256, 0, stream>>>(dstA, E, N, deg);
  k_scan<<<1, 256, 0, stream>>>(deg, N, row_start, cursor);
  k_scatter<<<(EN + 255) / 256, 256, 0, stream>>>(dstA, E, N, cursor, eid);
  k_loop_ea<<<N, 64, 0, stream>>>(ea, row_start, eid, E, loop_ea);

  dim3 mm((N + 63) / 64, THC / 64);

  // layer 1
  k_matmul<<<mm, 256, 0, stream>>>(x, W1, N, xp);
  k_al_sd<<<N, 256, 0, stream>>>(xp, as1, ad1, al_s, al_d);
  k_we<<<4, 256, 0, stream>>>(We1, ae1, w_e);
  k_al_e<<<(EN + 15) / 16, 256, 0, stream>>>(ea, loop_ea, w_e, E, EN, al_e);
  k_aggregate<<<N, 256, 0, stream>>>(xp, al_s, al_d, al_e, row_start, eid, srcA, E, b1, hbuf);

  // layer 2
  k_matmul<<<mm, 256, 0, stream>>>(hbuf, W2, N, xp);
  k_al_sd<<<N, 256, 0, stream>>>(xp, as2, ad2, al_s, al_d);
  k_we<<<4, 256, 0, stream>>>(We2, ae2, w_e);
  k_al_e<<<(EN + 15) / 16, 256, 0, stream>>>(ea, loop_ea, w_e, E, EN, al_e);
  k_aggregate<<<N, 256, 0, stream>>>(xp, al_s, al_d, al_e, row_start, eid, srcA, E, b2, (float*)d_out);
}

// Round 4
// 396.574 us; speedup vs baseline: 1.0780x; 1.0780x over previous
//
#include <hip/hip_runtime.h>

// GAT (2-layer, PyG GATConv semantics) on MI355X.
// N=20000 nodes, E=100000 edges (+N self-loops), D=64, H=16 heads, C=64 ch/head.
constexpr int TD  = 64;      // input feature dim
constexpr int TH  = 16;      // heads
constexpr int TC  = 64;      // channels per head
constexpr int THC = TH * TC; // 1024

// ---------------- CSR build (once, shared by both layers) ----------------

__global__ void k_zero_int(int* p, int n) {
  int i = blockIdx.x * blockDim.x + threadIdx.x;
  if (i < n) p[i] = 0;
}

__global__ void k_count_deg(const int* __restrict__ dst, int E, int N, int* __restrict__ deg) {
  int e = blockIdx.x * blockDim.x + threadIdx.x;
  if (e >= E + N) return;
  int d = (e < E) ? dst[e] : (e - E);   // self-loop edges e in [E, E+N)
  atomicAdd(&deg[d], 1);
}

// single-block exclusive scan over N degrees -> row_start[N+1], cursor copy
__global__ void k_scan(const int* __restrict__ deg, int N, int* __restrict__ row_start,
                       int* __restrict__ cursor) {
  __shared__ int part[256];
  int t = threadIdx.x;
  int chunk = (N + 255) / 256;
  int lo = t * chunk, hi = min(lo + chunk, N);
  int s = 0;
  for (int i = lo; i < hi; ++i) s += deg[i];
  part[t] = s;
  __syncthreads();
  if (t == 0) {
    int run = 0;
    for (int i = 0; i < 256; ++i) { int v = part[i]; part[i] = run; run += v; }
    row_start[N] = run;
  }
  __syncthreads();
  int run = part[t];
  for (int i = lo; i < hi; ++i) {
    row_start[i] = run; cursor[i] = run; run += deg[i];
  }
}

// scatter edge ids into CSR order; also materialize src node and dst node per position
__global__ void k_scatter(const int* __restrict__ src, const int* __restrict__ dst, int E, int N,
                          int* __restrict__ cursor, int* __restrict__ eid,
                          int* __restrict__ srcc, int* __restrict__ nid) {
  int e = blockIdx.x * blockDim.x + threadIdx.x;
  if (e >= E + N) return;
  int s, d;
  if (e < E) { s = src[e]; d = dst[e]; } else { s = d = e - E; }
  int pos = atomicAdd(&cursor[d], 1);
  eid[pos] = e; srcc[pos] = s; nid[pos] = d;
}

// ---------------- per-layer kernels ----------------

// xp = x[N,64] @ W[64,1024] (fp32 vector GEMM, 64x64 tiles, blockIdx.y == head)
// fused epilogue: al_s[n,h] = <xp[n,h,:], a_src[h,:]>, al_d likewise (tile == one head)
__global__ __launch_bounds__(256) void k_matmul(const float* __restrict__ x,
                                                const float* __restrict__ W,
                                                const float* __restrict__ a_src,
                                                const float* __restrict__ a_dst,
                                                int N, float* __restrict__ xp,
                                                float* __restrict__ al_s,
                                                float* __restrict__ al_d) {
  __shared__ float xs[64][65];   // +1 pad: conflict-free column reads
  __shared__ float ws[64][64];
  int r0 = blockIdx.x * 64;
  int h  = blockIdx.y;           // head == column tile (c0 = h*64)
  int c0 = h * 64;
  int tid = threadIdx.x;
  for (int idx = tid * 4; idx < 64 * 64; idx += 1024) {
    int r = idx >> 6, c = idx & 63;
    float4 v = make_float4(0.f, 0.f, 0.f, 0.f);
    if (r0 + r < N) v = *(const float4*)&x[(size_t)(r0 + r) * TD + c];
    xs[r][c] = v.x; xs[r][c + 1] = v.y; xs[r][c + 2] = v.z; xs[r][c + 3] = v.w;
    *(float4*)&ws[r][c] = *(const float4*)&W[(size_t)r * THC + c0 + c];  // r == k
  }
  __syncthreads();
  int ty = tid >> 4, tx = tid & 15;
  float acc[4][4] = {};
  for (int k = 0; k < 64; ++k) {
    float a0 = xs[ty * 4 + 0][k], a1 = xs[ty * 4 + 1][k];
    float a2 = xs[ty * 4 + 2][k], a3 = xs[ty * 4 + 3][k];
    float4 b = *(const float4*)&ws[k][tx * 4];
    acc[0][0] += a0 * b.x; acc[0][1] += a0 * b.y; acc[0][2] += a0 * b.z; acc[0][3] += a0 * b.w;
    acc[1][0] += a1 * b.x; acc[1][1] += a1 * b.y; acc[1][2] += a1 * b.z; acc[1][3] += a1 * b.w;
    acc[2][0] += a2 * b.x; acc[2][1] += a2 * b.y; acc[2][2] += a2 * b.z; acc[2][3] += a2 * b.w;
    acc[3][0] += a3 * b.x; acc[3][1] += a3 * b.y; acc[3][2] += a3 * b.z; acc[3][3] += a3 * b.w;
  }
  float4 asv = *(const float4*)&a_src[h * TC + tx * 4];
  float4 adv = *(const float4*)&a_dst[h * TC + tx * 4];
  for (int i = 0; i < 4; ++i) {
    int r = r0 + ty * 4 + i;
    float ps = acc[i][0] * asv.x + acc[i][1] * asv.y + acc[i][2] * asv.z + acc[i][3] * asv.w;
    float pd = acc[i][0] * adv.x + acc[i][1] * adv.y + acc[i][2] * adv.z + acc[i][3] * adv.w;
    for (int m = 8; m >= 1; m >>= 1) {
      ps += __shfl_xor(ps, m, 16);
      pd += __shfl_xor(pd, m, 16);
    }
    if (r < N) {
      *(float4*)&xp[(size_t)r * THC + c0 + tx * 4] =
          make_float4(acc[i][0], acc[i][1], acc[i][2], acc[i][3]);
      if (tx == 0) { al_s[r * TH + h] = ps; al_d[r * TH + h] = pd; }
    }
  }
}

// w_e[d,h] = sum_c We[d, h*64+c] * a_e[h,c]
__global__ void k_we(const float* __restrict__ We, const float* __restrict__ a_e,
                     float* __restrict__ w_e) {
  int t = blockIdx.x * blockDim.x + threadIdx.x;
  if (t >= TD * TH) return;
  int d = t >> 4, h = t & 15;
  float s = 0.f;
  for (int c = 0; c < TC; ++c) s += We[(size_t)d * THC + h * TC + c] * a_e[h * TC + c];
  w_e[d * TH + h] = s;
}

// ale[e,h] = <ea_row(e), w_e[:,h]> for REAL edges only (coalesced over e)
__global__ __launch_bounds__(256) void k_al_e(const float* __restrict__ ea,
                                              const float* __restrict__ w_e,
                                              int E, float* __restrict__ ale) {
  __shared__ float sea[16][64];
  __shared__ float swe[TD * TH];
  int tid = threadIdx.x;
  int e0 = blockIdx.x * 16;
  for (int i = tid; i < TD * TH; i += 256) swe[i] = w_e[i];
  {
    int idx = tid * 4;
    int le = idx >> 6, d = idx & 63;
    int e = e0 + le;
    float4 v = make_float4(0.f, 0.f, 0.f, 0.f);
    if (e < E) v = *(const float4*)&ea[(size_t)e * TD + d];
    *(float4*)&sea[le][d] = v;
  }
  __syncthreads();
  int le = tid >> 4, h = tid & 15;
  int e = e0 + le;
  if (e >= E) return;
  float s = 0.f;
  for (int dd = 0; dd < TD; ++dd) {
    int d = (dd + le * 8) & 63;              // rotate start: conflict-free LDS banks
    s += sea[le][d] * swe[d * TH + h];
  }
  ale[(size_t)e * TH + h] = s;
}

// self-loop ale = mean of incoming REAL edges' ale (linearity of ea @ w_e)
__global__ void k_loop_ale(const int* __restrict__ row_start, const int* __restrict__ eid,
                           const float* __restrict__ ale, int E, float* __restrict__ lale) {
  int n = blockIdx.x;
  int tid = threadIdx.x;                     // 64 = 16 heads x 4 lanes
  int h = tid & 15, lane = tid >> 4;
  int beg = row_start[n], end = row_start[n + 1];
  float s = 0.f; int c = 0;
  for (int i = beg + lane; i < end; i += 4) {
    int e = eid[i];
    if (e < E) { s += ale[(size_t)e * TH + h]; c++; }
  }
  s += __shfl_xor(s, 16); s += __shfl_xor(s, 32);
  c += __shfl_xor(c, 16); c += __shfl_xor(c, 32);
  if (lane == 0) lale[(size_t)n * TH + h] = s / (float)max(c, 1);
}

// alpha[h][i] (CSR position order) = leaky_relu(al_s[src]+al_d[dst]+al_e[edge])
__global__ __launch_bounds__(256) void k_alpha(const float* __restrict__ al_s,
                                               const float* __restrict__ al_d,
                                               const float* __restrict__ ale,
                                               const float* __restrict__ lale,
                                               const int* __restrict__ eid,
                                               const int* __restrict__ srcc,
                                               const int* __restrict__ nid,
                                               int E, int EN, float* __restrict__ alpha) {
  int tid = threadIdx.x;
  int h = tid & 15, il = tid >> 4;           // 16 positions per block, 16 heads
  int i = blockIdx.x * 16 + il;
  if (i >= EN) return;
  int e = eid[i], s = srcc[i], n = nid[i];
  float av = (e < E) ? ale[(size_t)e * TH + h] : lale[(size_t)(e - E) * TH + h];
  float a = al_s[s * TH + h] + al_d[n * TH + h] + av;
  a = (a > 0.f) ? a : 0.2f * a;
  alpha[(size_t)h * EN + i] = a;
}

// per-dst-node: parallel segment softmax (16 lanes/head) + weighted gather
__global__ __launch_bounds__(256) void k_aggregate(
    const float* __restrict__ xp, const float* __restrict__ alpha,
    const int* __restrict__ row_start, const int* __restrict__ srcc,
    int EN, const float* __restrict__ bias, float* __restrict__ out) {
  __shared__ float sw[TH][65];               // normalized weights (slots < 64)
  __shared__ float sm[TH], sdi[TH];
  __shared__ int   ssrc[64];
  __shared__ float red[THC];
  int n = blockIdx.x, tid = threadIdx.x;
  int h = tid >> 4, lane = tid & 15;
  int beg = row_start[n], end = row_start[n + 1];
  int deg = end - beg;

  // stage src ids (deg <= 64 fast path)
  if (tid < 64 && tid < deg) ssrc[tid] = srcc[beg + tid];

  // phase A: two-pass softmax, 16 lanes per head, coalesced alpha loads
  const float* ah = alpha + (size_t)h * EN;
  float areg[4];
  float mloc = -1e30f;
  int kcnt = 0;
  for (int i = beg + lane; i < end; i += 16, ++kcnt) {
    float a = ah[i];
    if (kcnt < 4) areg[kcnt] = a;
    mloc = fmaxf(mloc, a);
  }
  for (int m = 8; m >= 1; m >>= 1) mloc = fmaxf(mloc, __shfl_xor(mloc, m, 16));
  float dloc = 0.f;
  for (int k = 0; k < kcnt; ++k) {
    float a = (k < 4) ? areg[k] : ah[beg + lane + k * 16];
    dloc += expf(a - mloc);
  }
  for (int m = 8; m >= 1; m >>= 1) dloc += __shfl_xor(dloc, m, 16);
  float dinv = 1.f / (dloc + 1e-16f);
  for (int k = 0; k < kcnt; ++k) {
    int il = lane + k * 16;
    if (il < 64) {
      float a = (k < 4) ? areg[k] : ah[beg + il];
      sw[h][il] = expf(a - mloc) * dinv;
    }
  }
  if (lane == 0) { sm[h] = mloc; sdi[h] = dinv; }
  __syncthreads();

  // phase B: weighted gather of xp[src] rows (full 4KB row per edge across block)
  float4 acc = make_float4(0.f, 0.f, 0.f, 0.f);
  for (int i = beg; i < end; ++i) {
    int il = i - beg;
    int s = (il < 64) ? ssrc[il] : srcc[i];
    float w = (il < 64) ? sw[h][il] : expf(ah[i] - sm[h]) * sdi[h];
    float4 v = *(const float4*)&xp[(size_t)s * THC + h * TC + lane * 4];
    acc.x += w * v.x; acc.y += w * v.y; acc.z += w * v.z; acc.w += w * v.w;
  }
  *(float4*)&red[tid * 4] = acc;
  __syncthreads();
  if (tid < TC) {                            // head mean + bias + relu
    float s = 0.f;
    for (int hh = 0; hh < TH; ++hh) s += red[hh * TC + tid];
    s = s * (1.0f / TH) + bias[tid];
    out[(size_t)n * TC + tid] = fmaxf(s, 0.f);
  }
}

// ---------------- launch ----------------

extern "C" void kernel_launch(void* const* d_in, const int* in_sizes, int n_in,
                              void* d_out, int out_size, void* d_ws, size_t ws_size,
                              hipStream_t stream) {
  const float* x   = (const float*)d_in[0];
  const int*   ei  = (const int*)d_in[1];
  const float* ea  = (const float*)d_in[2];
  const float* W1  = (const float*)d_in[3];
  const float* as1 = (const float*)d_in[4];
  const float* ad1 = (const float*)d_in[5];
  const float* We1 = (const float*)d_in[6];
  const float* ae1 = (const float*)d_in[7];
  const float* b1  = (const float*)d_in[8];
  const float* W2  = (const float*)d_in[9];
  const float* as2 = (const float*)d_in[10];
  const float* ad2 = (const float*)d_in[11];
  const float* We2 = (const float*)d_in[12];
  const float* ae2 = (const float*)d_in[13];
  const float* b2  = (const float*)d_in[14];

  const int N  = in_sizes[0] / TD;   // 20000
  const int E  = in_sizes[1] / 2;    // 100000
  const int EN = E + N;              // 120000 (with self-loops)
  const int* srcA = ei;
  const int* dstA = ei + E;

  char* w = (char*)d_ws;
  auto alloc = [&](size_t bytes) {
    char* p = w;
    w += (bytes + 255) & ~(size_t)255;
    return p;
  };
  int*   deg       = (int*)alloc((size_t)N * 4);
  int*   row_start = (int*)alloc((size_t)(N + 1) * 4);
  int*   cursor    = (int*)alloc((size_t)N * 4);
  int*   eid       = (int*)alloc((size_t)EN * 4);
  int*   srcc      = (int*)alloc((size_t)EN * 4);
  int*   nid       = (int*)alloc((size_t)EN * 4);
  float* xp        = (float*)alloc((size_t)N * THC * 4);
  float* al_s      = (float*)alloc((size_t)N * TH * 4);
  float* al_d      = (float*)alloc((size_t)N * TH * 4);
  float* ale       = (float*)alloc((size_t)E * TH * 4);   // real edges only
  float* lale      = (float*)alloc((size_t)N * TH * 4);
  float* alpha     = (float*)alloc((size_t)TH * EN * 4);  // [H][EN], CSR order
  float* w_e       = (float*)alloc((size_t)TD * TH * 4);
  float* hbuf      = (float*)ale;   // overlay: ale is dead when hbuf is written,
                                    // and layer-2 k_al_e rewrites ale after matmul2 consumed hbuf

  // CSR by destination (shared by both layers)
  k_zero_int<<<(N + 255) / 256, 256, 0, stream>>>(deg, N);
  k_count_deg<<<(EN + 255) / 256, 256, 0, stream>>>(dstA, E, N, deg);
  k_scan<<<1, 256, 0, stream>>>(deg, N, row_start, cursor);
  k_scatter<<<(EN + 255) / 256, 256, 0, stream>>>(srcA, dstA, E, N, cursor, eid, srcc, nid);

  dim3 mm((N + 63) / 64, TH);

  // layer 1
  k_matmul<<<mm, 256, 0, stream>>>(x, W1, as1, ad1, N, xp, al_s, al_d);
  k_we<<<4, 256, 0, stream>>>(We1, ae1, w_e);
  k_al_e<<<(E + 15) / 16, 256, 0, stream>>>(ea, w_e, E, ale);
  k_loop_ale<<<N, 64, 0, stream>>>(row_start, eid, ale, E, lale);
  k_alpha<<<(EN + 15) / 16, 256, 0, stream>>>(al_s, al_d, ale, lale, eid, srcc, nid, E, EN, alpha);
  k_aggregate<<<N, 256, 0, stream>>>(xp, alpha, row_start, srcc, EN, b1, hbuf);

  // layer 2
  k_matmul<<<mm, 256, 0, stream>>>(hbuf, W2, as2, ad2, N, xp, al_s, al_d);
  k_we<<<4, 256, 0, stream>>>(We2, ae2, w_e);
  k_al_e<<<(E + 15) / 16, 256, 0, stream>>>(ea, w_e, E, ale);
  k_loop_ale<<<N, 64, 0, stream>>>(row_start, eid, ale, E, lale);
  k_alpha<<<(EN + 15) / 16, 256, 0, stream>>>(al_s, al_d, ale, lale, eid, srcc, nid, E, EN, alpha);
  k_aggregate<<<N, 256, 0, stream>>>(xp, alpha, row_start, srcc, EN, b2, (float*)d_out);
}

// Round 6
// 372.196 us; speedup vs baseline: 1.1486x; 1.0655x over previous
//
#include <hip/hip_runtime.h>

// GAT (2-layer, PyG GATConv semantics) on MI355X — src-major aggregation.
// N=20000 nodes, E=100000 edges (+N self-loops), D=64, H=16 heads, C=64 ch/head.
constexpr int TD  = 64;      // input feature dim
constexpr int TH  = 16;      // heads
constexpr int TC  = 64;      // channels per head
constexpr int THC = TH * TC; // 1024
constexpr int MAXP = 128;    // max in-degree cached in LDS (overflow -> global path)

// ---------------- CSR/CSC build (once, shared by both layers) ----------------

__global__ void k_zero_int(int* p, int n) {
  int i = blockIdx.x * blockDim.x + threadIdx.x;
  if (i < n) p[i] = 0;
}

// count in-degree (by dst) and out-degree (by src) in one pass; self-loops e in [E,E+N)
__global__ void k_count2(const int* __restrict__ src, const int* __restrict__ dst,
                         int E, int N, int* __restrict__ degd, int* __restrict__ degs) {
  int e = blockIdx.x * blockDim.x + threadIdx.x;
  if (e >= E + N) return;
  int s, d;
  if (e < E) { s = src[e]; d = dst[e]; } else { s = d = e - E; }
  atomicAdd(&degd[d], 1);
  atomicAdd(&degs[s], 1);
}

// two independent single-block exclusive scans (block 0: dst-CSR, block 1: src-CSR)
__global__ void k_scan2(const int* __restrict__ degd, int N,
                        int* __restrict__ row_start, int* __restrict__ cursor,
                        const int* __restrict__ degs,
                        int* __restrict__ srow, int* __restrict__ scursor) {
  const int* dg = blockIdx.x ? degs : degd;
  int* rs = blockIdx.x ? srow : row_start;
  int* cu = blockIdx.x ? scursor : cursor;
  __shared__ int part[256];
  int t = threadIdx.x;
  int chunk = (N + 255) / 256;
  int lo = t * chunk, hi = min(lo + chunk, N);
  int s = 0;
  for (int i = lo; i < hi; ++i) s += dg[i];
  part[t] = s;
  __syncthreads();
  if (t == 0) {
    int run = 0;
    for (int i = 0; i < 256; ++i) { int v = part[i]; part[i] = run; run += v; }
    rs[N] = run;
  }
  __syncthreads();
  int run = part[t];
  for (int i = lo; i < hi; ++i) {
    rs[i] = run; cu[i] = run; run += dg[i];
  }
}

// dst-CSR scatter: position i holds edge eid[i] with source srcc[i]; inv[e] = i
__global__ void k_scatter_dst(const int* __restrict__ src, const int* __restrict__ dst,
                              int E, int N, int* __restrict__ cursor,
                              int* __restrict__ eid, int* __restrict__ srcc,
                              int* __restrict__ inv) {
  int e = blockIdx.x * blockDim.x + threadIdx.x;
  if (e >= E + N) return;
  int s, d;
  if (e < E) { s = src[e]; d = dst[e]; } else { s = d = e - E; }
  int pos = atomicAdd(&cursor[d], 1);
  eid[pos] = e; srcc[pos] = s; inv[e] = pos;
}

// src-CSR scatter: smap[j] = dst-CSR position of the j-th out-edge
__global__ void k_scatter_src(const int* __restrict__ src, int E, int N,
                              int* __restrict__ scursor, const int* __restrict__ inv,
                              int* __restrict__ smap) {
  int e = blockIdx.x * blockDim.x + threadIdx.x;
  if (e >= E + N) return;
  int s = (e < E) ? src[e] : (e - E);
  int j = atomicAdd(&scursor[s], 1);
  smap[j] = inv[e];
}

// ---------------- per-layer kernels ----------------

// xp = x[N,64] @ W[64,1024] (fp32 vector GEMM, 64x64 tiles, blockIdx.y == head)
// fused epilogue: al_s[n,h] = <xp[n,h,:], a_src[h,:]>, al_d likewise (tile == one head).
// x-tile stored k-major with XOR swizzle S(k)=k&28: A-fragment loads become aligned
// conflict-free ds_read_b128 (write word kk*64 + (r^S(kk)); read k*64 + ((4ty)^S(k))).
__global__ __launch_bounds__(256) void k_matmul(const float* __restrict__ x,
                                                const float* __restrict__ W,
                                                const float* __restrict__ a_src,
                                                const float* __restrict__ a_dst,
                                                int N, float* __restrict__ xp,
                                                float* __restrict__ al_s,
                                                float* __restrict__ al_d) {
  __shared__ float xs[64 * 64];  // k-major, swizzled
  __shared__ float ws[64][64];
  int r0 = blockIdx.x * 64;
  int h  = blockIdx.y;           // head == column tile (c0 = h*64)
  int c0 = h * 64;
  int tid = threadIdx.x;
  for (int idx = tid * 4; idx < 64 * 64; idx += 1024) {
    int r = idx >> 6, c = idx & 63;          // c multiple of 4
    float4 v = make_float4(0.f, 0.f, 0.f, 0.f);
    if (r0 + r < N) v = *(const float4*)&x[(size_t)(r0 + r) * TD + c];
    xs[(c + 0) * 64 + (r ^ ((c + 0) & 28))] = v.x;
    xs[(c + 1) * 64 + (r ^ ((c + 1) & 28))] = v.y;
    xs[(c + 2) * 64 + (r ^ ((c + 2) & 28))] = v.z;
    xs[(c + 3) * 64 + (r ^ ((c + 3) & 28))] = v.w;
    *(float4*)&ws[r][c] = *(const float4*)&W[(size_t)r * THC + c0 + c];  // r == k
  }
  __syncthreads();
  int ty = tid >> 4, tx = tid & 15;
  float acc[4][4] = {};
  for (int k = 0; k < 64; ++k) {
    float4 a = *(const float4*)&xs[k * 64 + ((ty * 4) ^ (k & 28))];
    float4 b = *(const float4*)&ws[k][tx * 4];
    acc[0][0] += a.x * b.x; acc[0][1] += a.x * b.y; acc[0][2] += a.x * b.z; acc[0][3] += a.x * b.w;
    acc[1][0] += a.y * b.x; acc[1][1] += a.y * b.y; acc[1][2] += a.y * b.z; acc[1][3] += a.y * b.w;
    acc[2][0] += a.z * b.x; acc[2][1] += a.z * b.y; acc[2][2] += a.z * b.z; acc[2][3] += a.z * b.w;
    acc[3][0] += a.w * b.x; acc[3][1] += a.w * b.y; acc[3][2] += a.w * b.z; acc[3][3] += a.w * b.w;
  }
  float4 asv = *(const float4*)&a_src[h * TC + tx * 4];
  float4 adv = *(const float4*)&a_dst[h * TC + tx * 4];
  for (int i = 0; i < 4; ++i) {
    int r = r0 + ty * 4 + i;
    float ps = acc[i][0] * asv.x + acc[i][1] * asv.y + acc[i][2] * asv.z + acc[i][3] * asv.w;
    float pd = acc[i][0] * adv.x + acc[i][1] * adv.y + acc[i][2] * adv.z + acc[i][3] * adv.w;
    for (int m = 8; m >= 1; m >>= 1) {
      ps += __shfl_xor(ps, m, 16);
      pd += __shfl_xor(pd, m, 16);
    }
    if (r < N) {
      *(float4*)&xp[(size_t)r * THC + c0 + tx * 4] =
          make_float4(acc[i][0], acc[i][1], acc[i][2], acc[i][3]);
      if (tx == 0) { al_s[r * TH + h] = ps; al_d[r * TH + h] = pd; }
    }
  }
}

// w_e[d,h] = sum_c We[d, h*64+c] * a_e[h,c]
__global__ void k_we(const float* __restrict__ We, const float* __restrict__ a_e,
                     float* __restrict__ w_e) {
  int t = blockIdx.x * blockDim.x + threadIdx.x;
  if (t >= TD * TH) return;
  int d = t >> 4, h = t & 15;
  float s = 0.f;
  for (int c = 0; c < TC; ++c) s += We[(size_t)d * THC + h * TC + c] * a_e[h * TC + c];
  w_e[d * TH + h] = s;
}

// ale[e,h] = <ea_row(e), w_e[:,h]> for REAL edges only (coalesced over e)
__global__ __launch_bounds__(256) void k_al_e(const float* __restrict__ ea,
                                              const float* __restrict__ w_e,
                                              int E, float* __restrict__ ale) {
  __shared__ float sea[16][64];
  __shared__ float swe[TD * TH];
  int tid = threadIdx.x;
  int e0 = blockIdx.x * 16;
  for (int i = tid; i < TD * TH; i += 256) swe[i] = w_e[i];
  {
    int idx = tid * 4;
    int le = idx >> 6, d = idx & 63;
    int e = e0 + le;
    float4 v = make_float4(0.f, 0.f, 0.f, 0.f);
    if (e < E) v = *(const float4*)&ea[(size_t)e * TD + d];
    *(float4*)&sea[le][d] = v;
  }
  __syncthreads();
  int le = tid >> 4, h = tid & 15;
  int e = e0 + le;
  if (e >= E) return;
  float s = 0.f;
  for (int dd = 0; dd < TD; ++dd) {
    int d = (dd + le * 8) & 63;              // rotate start: conflict-free LDS banks
    s += sea[le][d] * swe[d * TH + h];
  }
  ale[(size_t)e * TH + h] = s;
}

// per-dst block: self-loop ale mean (linearity) + alpha + segment softmax,
// writes normalized att[i][h] in dst-CSR position order. 256 thr = 16 pos-slots x 16 heads.
__global__ __launch_bounds__(256) void k_att(
    const float* __restrict__ al_s, const float* __restrict__ al_d,
    const float* __restrict__ ale, const int* __restrict__ row_start,
    const int* __restrict__ eid, const int* __restrict__ srcc,
    int E, float* __restrict__ att) {
  __shared__ float sal[MAXP][TH];            // 8 KB: alpha per cached position
  __shared__ float sred[16][TH + 1];
  __shared__ float sLale[TH], sM[TH], sDi[TH];
  __shared__ int sSelfP;
  int n = blockIdx.x, tid = threadIdx.x;
  int h = tid & 15, q = tid >> 4;
  int beg = row_start[n], end = row_start[n + 1], deg = end - beg;
  float ald = al_d[n * TH + h];

  if (tid == 0) sSelfP = -1;
  __syncthreads();

  // pass 1: gather al_s[src]+ald (+ale for real edges); accumulate ale-sum
  float asum = 0.f;
  for (int p = q; p < deg; p += 16) {
    int i = beg + p;
    int e = eid[i], s = srcc[i];
    float av = 0.f;
    if (e < E) { av = ale[(size_t)e * TH + h]; asum += av; }
    else if (h == 0) sSelfP = p;             // exactly one self-loop per node
    if (p < MAXP) sal[p][h] = al_s[s * TH + h] + ald + av;
  }
  sred[q][h] = asum;
  __syncthreads();
  if (q == 0) {
    float t = 0.f;
    for (int qq = 0; qq < 16; ++qq) t += sred[qq][h];
    sLale[h] = t / (float)max(deg - 1, 1);   // mean ale of real in-edges
  }
  __syncthreads();

  int selfp = sSelfP;
  auto full_a = [&](int i) -> float {        // overflow path (deg > MAXP), exact math
    int e = eid[i], s = srcc[i];
    float av = (e < E) ? ale[(size_t)e * TH + h] : sLale[h];
    float a = al_s[s * TH + h] + ald + av;
    return (a > 0.f) ? a : 0.2f * a;
  };

  // pass 2: finalize alpha (add lale to self, leaky_relu), partial max
  float mloc = -1e30f;
  for (int p = q; p < deg; p += 16) {
    float a;
    if (p < MAXP) {
      a = sal[p][h];
      if (p == selfp) a += sLale[h];
      a = (a > 0.f) ? a : 0.2f * a;
      sal[p][h] = a;
    } else a = full_a(beg + p);
    mloc = fmaxf(mloc, a);
  }
  sred[q][h] = mloc;
  __syncthreads();
  if (q == 0) {
    float m = -1e30f;
    for (int qq = 0; qq < 16; ++qq) m = fmaxf(m, sred[qq][h]);
    sM[h] = m;
  }
  __syncthreads();

  // pass 3: partial denominator
  float dloc = 0.f;
  for (int p = q; p < deg; p += 16) {
    float a = (p < MAXP) ? sal[p][h] : full_a(beg + p);
    dloc += expf(a - sM[h]);
  }
  sred[q][h] = dloc;
  __syncthreads();
  if (q == 0) {
    float d = 0.f;
    for (int qq = 0; qq < 16; ++qq) d += sred[qq][h];
    sDi[h] = 1.f / (d + 1e-16f);
  }
  __syncthreads();

  // pass 4: write normalized attention (coalesced 64B chunks per position)
  for (int p = q; p < deg; p += 16) {
    float a = (p < MAXP) ? sal[p][h] : full_a(beg + p);
    att[(size_t)(beg + p) * TH + h] = expf(a - sM[h]) * sDi[h];
  }
}

// src-major: stage xp[s] once in LDS; per out-edge fold heads:
// z[i][c] = sum_h att[i,h] * xp[s,h,c], written in dst-CSR position order.
__global__ __launch_bounds__(256) void k_csc_z(const float* __restrict__ xp,
                                               const float* __restrict__ att,
                                               const int* __restrict__ srow,
                                               const int* __restrict__ smap,
                                               float* __restrict__ z) {
  __shared__ float sx[THC];                  // 4 KB
  int s = blockIdx.x, tid = threadIdx.x;
  int beg = srow[s], end = srow[s + 1];
  *(float4*)&sx[tid * 4] = *(const float4*)&xp[(size_t)s * THC + tid * 4];
  __syncthreads();
  int slot = tid >> 6, c = tid & 63;
  for (int j = beg + slot; j < end; j += 4) {
    int i = smap[j];
    const float* ar = &att[(size_t)i * TH];
    float acc = 0.f;
#pragma unroll
    for (int hh = 0; hh < TH; ++hh) acc += ar[hh] * sx[hh * 64 + c];
    z[(size_t)i * 64 + c] = acc;
  }
}

// per-dst: sum contiguous z segment, head-mean + bias + relu
__global__ __launch_bounds__(256) void k_sum_z(const float* __restrict__ z,
                                               const int* __restrict__ row_start,
                                               const float* __restrict__ bias, int N,
                                               float* __restrict__ out) {
  int tid = threadIdx.x;
  int n = blockIdx.x * 4 + (tid >> 6);
  int c = tid & 63;
  if (n >= N) return;
  int beg = row_start[n], end = row_start[n + 1];
  float acc = 0.f;
  for (int i = beg; i < end; ++i) acc += z[(size_t)i * 64 + c];
  out[(size_t)n * 64 + c] = fmaxf(acc * (1.0f / TH) + bias[c], 0.f);
}

// ---------------- launch ----------------

extern "C" void kernel_launch(void* const* d_in, const int* in_sizes, int n_in,
                              void* d_out, int out_size, void* d_ws, size_t ws_size,
                              hipStream_t stream) {
  const float* x   = (const float*)d_in[0];
  const int*   ei  = (const int*)d_in[1];
  const float* ea  = (const float*)d_in[2];
  const float* W1  = (const float*)d_in[3];
  const float* as1 = (const float*)d_in[4];
  const float* ad1 = (const float*)d_in[5];
  const float* We1 = (const float*)d_in[6];
  const float* ae1 = (const float*)d_in[7];
  const float* b1  = (const float*)d_in[8];
  const float* W2  = (const float*)d_in[9];
  const float* as2 = (const float*)d_in[10];
  const float* ad2 = (const float*)d_in[11];
  const float* We2 = (const float*)d_in[12];
  const float* ae2 = (const float*)d_in[13];
  const float* b2  = (const float*)d_in[14];

  const int N  = in_sizes[0] / TD;   // 20000
  const int E  = in_sizes[1] / 2;    // 100000
  const int EN = E + N;              // 120000 (with self-loops)
  const int* srcA = ei;
  const int* dstA = ei + E;

  char* w = (char*)d_ws;
  auto alloc = [&](size_t bytes) {
    char* p = w;
    w += (bytes + 255) & ~(size_t)255;
    return p;
  };
  int*   deg2      = (int*)alloc((size_t)2 * N * 4);      // degd | degs
  int*   degd      = deg2;
  int*   degs      = deg2 + N;
  int*   row_start = (int*)alloc((size_t)(N + 1) * 4);
  int*   srow      = (int*)alloc((size_t)(N + 1) * 4);
  int*   cursor    = (int*)alloc((size_t)N * 4);
  int*   scursor   = (int*)alloc((size_t)N * 4);
  int*   eid       = (int*)alloc((size_t)EN * 4);
  int*   srcc      = (int*)alloc((size_t)EN * 4);
  int*   inv       = (int*)alloc((size_t)EN * 4);
  int*   smap      = (int*)alloc((size_t)EN * 4);
  float* xp        = (float*)alloc((size_t)N * THC * 4);  // 82 MB
  float* al_s      = (float*)alloc((size_t)N * TH * 4);
  float* al_d      = (float*)alloc((size_t)N * TH * 4);
  float* ale       = (float*)alloc((size_t)E * TH * 4);   // 6.4 MB, real edges only
  float* att       = (float*)alloc((size_t)EN * TH * 4);  // 7.7 MB
  float* z         = (float*)alloc((size_t)EN * TC * 4);  // 30.7 MB
  float* w_e       = (float*)alloc((size_t)TD * TH * 4);
  float* hbuf      = (float*)ale;  // overlay: ale dead after k_att; layer-2 k_al_e
                                   // rewrites ale only after matmul2 consumed hbuf

  // CSR (by dst) + CSC (by src) build, shared by both layers
  k_zero_int<<<(2 * N + 255) / 256, 256, 0, stream>>>(deg2, 2 * N);
  k_count2<<<(EN + 255) / 256, 256, 0, stream>>>(srcA, dstA, E, N, degd, degs);
  k_scan2<<<2, 256, 0, stream>>>(degd, N, row_start, cursor, degs, srow, scursor);
  k_scatter_dst<<<(EN + 255) / 256, 256, 0, stream>>>(srcA, dstA, E, N, cursor, eid, srcc, inv);
  k_scatter_src<<<(EN + 255) / 256, 256, 0, stream>>>(srcA, E, N, scursor, inv, smap);

  dim3 mm((N + 63) / 64, TH);

  // layer 1
  k_matmul<<<mm, 256, 0, stream>>>(x, W1, as1, ad1, N, xp, al_s, al_d);
  k_we<<<4, 256, 0, stream>>>(We1, ae1, w_e);
  k_al_e<<<(E + 15) / 16, 256, 0, stream>>>(ea, w_e, E, ale);
  k_att<<<N, 256, 0, stream>>>(al_s, al_d, ale, row_start, eid, srcc, E, att);
  k_csc_z<<<N, 256, 0, stream>>>(xp, att, srow, smap, z);
  k_sum_z<<<(N + 3) / 4, 256, 0, stream>>>(z, row_start, b1, N, hbuf);

  // layer 2
  k_matmul<<<mm, 256, 0, stream>>>(hbuf, W2, as2, ad2, N, xp, al_s, al_d);
  k_we<<<4, 256, 0, stream>>>(We2, ae2, w_e);
  k_al_e<<<(E + 15) / 16, 256, 0, stream>>>(ea, w_e, E, ale);
  k_att<<<N, 256, 0, stream>>>(al_s, al_d, ale, row_start, eid, srcc, E, att);
  k_csc_z<<<N, 256, 0, stream>>>(xp, att, srow, smap, z);
  k_sum_z<<<(N + 3) / 4, 256, 0, stream>>>(z, row_start, b2, N, (float*)d_out);
}